// Round 19
// baseline (497.696 us; speedup 1.0000x reference)
//
#include <hip/hip_runtime.h>
#include <stdint.h>

#define HW 9216   // 96*96

typedef float f32x4 __attribute__((ext_vector_type(4)));
typedef short s16x8 __attribute__((ext_vector_type(8)));

#define PIN() asm volatile("" ::: "memory")
#define WAITV12() asm volatile("s_waitcnt vmcnt(12)" ::: "memory")

__device__ __forceinline__ unsigned short f2bf(float f){
  union { float fv; uint32_t u; } x; x.fv = f;
  uint32_t u = x.u;
  u += 0x7fffu + ((u >> 16) & 1u);   // RNE
  return (unsigned short)(u >> 16);
}
__device__ __forceinline__ float bf2f(unsigned short s){
  union { uint32_t u; float fv; } x; x.u = ((uint32_t)s) << 16;
  return x.fv;
}

__device__ __forceinline__ void gload16(const void* g, void* l){
  __builtin_amdgcn_global_load_lds(
    (const __attribute__((address_space(1))) unsigned int*)g,
    (__attribute__((address_space(3))) unsigned int*)l, 16, 0, 0);
}

// ------- fused: NCHW->NHWC transpose (blocks 0..2303, pad 65 = 4-way reads) + packs + zp -------
__global__ __launch_bounds__(256) void transp_pack_kernel(const float* __restrict__ x,
    unsigned short* __restrict__ xT,
    const float* __restrict__ w_in, const float* __restrict__ w_out,
    const float* __restrict__ w_cls1, unsigned short* __restrict__ WpIn,
    unsigned short* __restrict__ WpOut, unsigned short* __restrict__ WpCls,
    unsigned short* __restrict__ zp){
  __shared__ unsigned short tl[256 * 65];
  int blk = blockIdx.x;
  int tid = threadIdx.x;
  if (blk < 2304){
    int b = blk / 1152; int r = blk - b * 1152;
    int cchunk = r / 144, pxt = r - cchunk * 144;
    int c0 = cchunk * 256, px0 = pxt * 64;
    for (int e = tid; e < 4096; e += 256){
      int cc = e >> 4, pq = e & 15;
      float4 v4 = *(const float4*)(x + ((size_t)(b * 2048 + c0 + cc)) * HW + px0 + pq * 4);
      const float* vp = (const float*)&v4;
      #pragma unroll
      for (int j = 0; j < 4; j++) tl[cc * 65 + pq * 4 + j] = f2bf(vp[j]);
    }
    __syncthreads();
    for (int j = tid; j < 2048; j += 256){
      int px = j >> 5, oct = j & 31;
      s16x8 pk;
      #pragma unroll
      for (int t = 0; t < 8; t++) pk[t] = (short)tl[(oct * 8 + t) * 65 + px];
      *(s16x8*)(xT + ((size_t)(b * 9216 + px0 + px)) * 2048 + c0 + oct * 8) = pk;
    }
  } else {
    if (blk == 2304 && tid < 64) ((unsigned int*)zp)[tid] = 0u;
    const int N0 = 64 * 2048 * 9, N1 = 64 * 64 * 9, N2 = 64 * 2112 * 9;
    int total = N0 + N1 + N2;
    int nblk = gridDim.x - 2304;
    for (int i = (blk - 2304) * 256 + tid; i < total; i += nblk * 256){
      const float* w; unsigned short* Wp; int Cin; int idx;
      if (i < N0){ w = w_in; Wp = WpIn; Cin = 2048; idx = i; }
      else if (i < N0 + N1){ w = w_out; Wp = WpOut; Cin = 64; idx = i - N0; }
      else { w = w_cls1; Wp = WpCls; Cin = 2112; idx = i - N0 - N1; }
      int c = idx & 31; int r = idx >> 5; int o = r & 63; int r2 = r >> 6;
      int tap = r2 % 9; int ck = r2 / 9;
      Wp[idx] = f2bf(w[((size_t)o * Cin + ck * 32 + c) * 9 + tap]);
    }
  }
}

// -------- per-tap body: NMF rows/wave, 4 ds_read + NMF*4 MFMA + rolling B prefetch --------
template<int T, int NMF>
__device__ __forceinline__ void tapbody(const char* hb, s16x8 (&bs)[4], f32x4 (&acc)[NMF][4],
    const unsigned short* wbase, int gmax, int g0, int rowbase, int ln, int kg){
  constexpr int dy = T / 3, dx = T - dy * 3;
  #pragma unroll
  for (int mf = 0; mf < NMF; mf++){
    int p = (rowbase + mf + dy) * 18 + (ln + dx);
    int aoff = p * 64 + ((kg ^ (p & 3)) << 4);
    s16x8 a = *(const s16x8*)(hb + aoff);
    #pragma unroll
    for (int nf = 0; nf < 4; nf++)
      acc[mf][nf] = __builtin_amdgcn_mfma_f32_16x16x32_bf16(a, bs[nf], acc[mf][nf], 0, 0, 0);
  }
  constexpr int dck = (T + 3) / 9, dt = (T + 3) % 9;
  if (g0 + T + 3 < gmax){
    const unsigned short* wb2 = wbase + dck * 18432 + dt * 2048;
    #pragma unroll
    for (int nf = 0; nf < 4; nf++) bs[nf] = *(const s16x8*)(wb2 + nf * 512);
  }
}

// ---------------- conv3x3 NHWC implicit GEMM: 512 threads (8 waves, 2 rows each) ----------------
// Same tile/KS/LDS/dataflow as the round-12 proven config; 2x waves/CU for latency hiding.
__global__ __launch_bounds__(512, 4) void conv_nhwc_kernel(
    const unsigned short* __restrict__ A0, int c0stride,
    const unsigned short* __restrict__ A1, int nck0,
    const unsigned short* __restrict__ Wp,
    unsigned short* __restrict__ sl, int nchunks,
    const unsigned short* __restrict__ zp){
  int mt = blockIdx.x;
  int b = mt / 36; int r = mt - b * 36;
  int h0 = (r / 6) * 16, w0 = (r % 6) * 16;
  int KS = gridDim.y, ks = blockIdx.y;
  int c0 = (nchunks * ks) / KS, c1 = (nchunks * (ks + 1)) / KS;
  int tid = threadIdx.x, lane = tid & 63, wv = tid >> 6;
  int ln = lane & 15, kg = lane >> 4;
  __shared__ char halo[2][24576];

  int pixb0[3], pixb1[3]; bool val[3];
  #pragma unroll
  for (int rr = 0; rr < 3; rr++){
    int i = tid + rr * 512;
    int p = i >> 2, q_lds = i & 3;
    int logq = q_lds ^ (p & 3);
    int hh = p / 18, ww = p - hh * 18;
    int h = h0 - 1 + hh, w = w0 - 1 + ww;
    bool v = (i < 1296) && ((unsigned)h < 96u) && ((unsigned)w < 96u);
    val[rr] = v;
    int pix = (b * 96 + h) * 96 + w;
    pixb0[rr] = v ? (pix * c0stride * 2 + logq * 16) : 0;
    pixb1[rr] = v ? (pix * 128 + logq * 16) : 0;
  }
  const char* a0B = (const char*)A0;
  const char* a1B = (const char*)A1;
  const char* zpB = (const char*)zp;

  auto stage = [&](char* ldsB, int ck){
    bool inA0 = (ck < nck0);
    int chb0 = ck * 64, chb1 = (ck - nck0) * 64;
    #pragma unroll
    for (int rr = 0; rr < 3; rr++){
      const char* src = zpB;
      if (val[rr]) src = inA0 ? (a0B + pixb0[rr] + chb0) : (a1B + pixb1[rr] + chb1);
      gload16(src, ldsB + (tid + rr * 512) * 16);
    }
  };

  f32x4 acc[2][4];
  #pragma unroll
  for (int i = 0; i < 2; i++)
    #pragma unroll
    for (int j = 0; j < 4; j++) acc[i][j] = (f32x4)(0.f);

  s16x8 bs0[4], bs1[4], bs2[4];
  int gmax = (c1 - c0) * 9;
  int rowbase = wv * 2;

  stage(&halo[0][0], c0);
  PIN();
  {
    const unsigned short* w0b = Wp + (size_t)c0 * 18432 + ln * 32 + kg * 8;
    #pragma unroll
    for (int nf = 0; nf < 4; nf++){
      bs0[nf] = *(const s16x8*)(w0b + 0 * 2048 + nf * 512);
      bs1[nf] = *(const s16x8*)(w0b + 1 * 2048 + nf * 512);
      bs2[nf] = *(const s16x8*)(w0b + 2 * 2048 + nf * 512);
    }
  }
  WAITV12();
  __builtin_amdgcn_s_barrier();

  for (int ck = c0; ck < c1; ck++){
    int cur = (ck - c0) & 1;
    if (ck + 1 < c1){ stage(&halo[cur ^ 1][0], ck + 1); PIN(); }
    const unsigned short* wbase = Wp + (size_t)ck * 18432 + ln * 32 + kg * 8;
    const char* hb = &halo[cur][0];
    int g0 = (ck - c0) * 9;
    tapbody<0,2>(hb, bs0, acc, wbase, gmax, g0, rowbase, ln, kg);
    tapbody<1,2>(hb, bs1, acc, wbase, gmax, g0, rowbase, ln, kg);
    tapbody<2,2>(hb, bs2, acc, wbase, gmax, g0, rowbase, ln, kg);
    tapbody<3,2>(hb, bs0, acc, wbase, gmax, g0, rowbase, ln, kg);
    tapbody<4,2>(hb, bs1, acc, wbase, gmax, g0, rowbase, ln, kg);
    tapbody<5,2>(hb, bs2, acc, wbase, gmax, g0, rowbase, ln, kg);
    tapbody<6,2>(hb, bs0, acc, wbase, gmax, g0, rowbase, ln, kg);
    tapbody<7,2>(hb, bs1, acc, wbase, gmax, g0, rowbase, ln, kg);
    tapbody<8,2>(hb, bs2, acc, wbase, gmax, g0, rowbase, ln, kg);
    if (ck + 1 < c1){
      WAITV12();
      __builtin_amdgcn_s_barrier();
    }
  }

  unsigned short* base = sl + ((size_t)(ks * 72 + mt)) * 16384;
  #pragma unroll
  for (int mf = 0; mf < 2; mf++)
    #pragma unroll
    for (int nf = 0; nf < 4; nf++){
      int o = nf * 16 + ln;
      #pragma unroll
      for (int rr = 0; rr < 4; rr++){
        int m = (rowbase + mf) * 16 + kg * 4 + rr;
        base[m * 64 + o] = f2bf(acc[mf][nf][rr]);
      }
    }
}

// ---------------- conv_out (64->64, 2 chunks, KS=1, 256 thr) with fused BN+ReLU ----------------
__global__ __launch_bounds__(256, 2) void conv_out_kernel(
    const unsigned short* __restrict__ A0,
    const unsigned short* __restrict__ Wp,
    const float* __restrict__ g, const float* __restrict__ bb,
    const float* __restrict__ mm, const float* __restrict__ vv,
    unsigned short* __restrict__ outT,
    const unsigned short* __restrict__ zp){
  int mt = blockIdx.x;
  int b = mt / 36; int r = mt - b * 36;
  int h0 = (r / 6) * 16, w0 = (r % 6) * 16;
  int tid = threadIdx.x, lane = tid & 63, wv = tid >> 6;
  int ln = lane & 15, kg = lane >> 4;
  __shared__ char halo[2][24576];

  int pixb0[6]; bool val[6];
  #pragma unroll
  for (int rr = 0; rr < 6; rr++){
    int i = tid + rr * 256;
    int p = i >> 2, q_lds = i & 3;
    int logq = q_lds ^ (p & 3);
    int hh = p / 18, ww = p - hh * 18;
    int h = h0 - 1 + hh, w = w0 - 1 + ww;
    bool v = (i < 1296) && ((unsigned)h < 96u) && ((unsigned)w < 96u);
    val[rr] = v;
    int pix = (b * 96 + h) * 96 + w;
    pixb0[rr] = v ? (pix * 128 + logq * 16) : 0;
  }
  const char* a0B = (const char*)A0;
  const char* zpB = (const char*)zp;

  auto stage = [&](char* ldsB, int ck){
    int chb0 = ck * 64;
    #pragma unroll
    for (int rr = 0; rr < 6; rr++){
      const char* src = val[rr] ? (a0B + pixb0[rr] + chb0) : zpB;
      gload16(src, ldsB + (tid + rr * 256) * 16);
    }
  };

  f32x4 acc[4][4];
  #pragma unroll
  for (int i = 0; i < 4; i++)
    #pragma unroll
    for (int j = 0; j < 4; j++) acc[i][j] = (f32x4)(0.f);

  s16x8 bs0[4], bs1[4], bs2[4];
  int rowbase = wv * 4;

  stage(&halo[0][0], 0);
  PIN();
  {
    const unsigned short* w0b = Wp + ln * 32 + kg * 8;
    #pragma unroll
    for (int nf = 0; nf < 4; nf++){
      bs0[nf] = *(const s16x8*)(w0b + 0 * 2048 + nf * 512);
      bs1[nf] = *(const s16x8*)(w0b + 1 * 2048 + nf * 512);
      bs2[nf] = *(const s16x8*)(w0b + 2 * 2048 + nf * 512);
    }
  }
  WAITV12();
  __builtin_amdgcn_s_barrier();

  for (int ck = 0; ck < 2; ck++){
    int cur = ck & 1;
    if (ck == 0){ stage(&halo[1][0], 1); PIN(); }
    const unsigned short* wbase = Wp + (size_t)ck * 18432 + ln * 32 + kg * 8;
    const char* hb = &halo[cur][0];
    int g0 = ck * 9;
    tapbody<0,4>(hb, bs0, acc, wbase, 18, g0, rowbase, ln, kg);
    tapbody<1,4>(hb, bs1, acc, wbase, 18, g0, rowbase, ln, kg);
    tapbody<2,4>(hb, bs2, acc, wbase, 18, g0, rowbase, ln, kg);
    tapbody<3,4>(hb, bs0, acc, wbase, 18, g0, rowbase, ln, kg);
    tapbody<4,4>(hb, bs1, acc, wbase, 18, g0, rowbase, ln, kg);
    tapbody<5,4>(hb, bs2, acc, wbase, 18, g0, rowbase, ln, kg);
    tapbody<6,4>(hb, bs0, acc, wbase, 18, g0, rowbase, ln, kg);
    tapbody<7,4>(hb, bs1, acc, wbase, 18, g0, rowbase, ln, kg);
    tapbody<8,4>(hb, bs2, acc, wbase, 18, g0, rowbase, ln, kg);
    if (ck == 0){
      WAITV12();
      __builtin_amdgcn_s_barrier();
    }
  }

  #pragma unroll
  for (int nf = 0; nf < 4; nf++){
    int o = nf * 16 + ln;
    float sc = g[o] * rsqrtf(vv[o] + 1e-5f);
    float mo = mm[o], bo = bb[o];
    #pragma unroll
    for (int mf = 0; mf < 4; mf++)
      #pragma unroll
      for (int rr = 0; rr < 4; rr++){
        int m = (rowbase + mf) * 16 + kg * 4 + rr;
        int h = h0 + (m >> 4), w = w0 + (m & 15);
        float valf = (acc[mf][nf][rr] - mo) * sc + bo;
        valf = fmaxf(valf, 0.f);
        outT[(((size_t)b * 96 + h) * 96 + w) * 64 + o] = f2bf(valf);
      }
  }
}

// ---------------- K-split reduce + BN (+ReLU) -> NHWC bf16; optional fused q/k/v proj ----------------
__global__ __launch_bounds__(256) void bn_reduce_kernel(const unsigned short* __restrict__ sl,
    int KS, const float* __restrict__ g, const float* __restrict__ bb,
    const float* __restrict__ mm, const float* __restrict__ vv, int relu,
    unsigned short* __restrict__ out, int do_proj,
    const float* __restrict__ wq, const float* __restrict__ wk, const float* __restrict__ wv,
    float* __restrict__ q, float* __restrict__ k, unsigned short* __restrict__ v){
  __shared__ float yl[4 * 65];
  __shared__ float wqL[8 * 65], wkL[8 * 65], wvL[64 * 65];
  int tid = threadIdx.x;
  if (do_proj){
    for (int i = tid; i < 512; i += 256){
      int d = i >> 6, c = i & 63;
      wqL[d * 65 + c] = wq[i]; wkL[d * 65 + c] = wk[i];
    }
    for (int i = tid; i < 4096; i += 256){
      int o = i >> 6, c = i & 63;
      wvL[o * 65 + c] = wv[i];
    }
  }
  int idx = blockIdx.x * 256 + tid;
  int mt = idx >> 14, e = idx & 16383;
  int m = e >> 6, o = e & 63;
  float s = 0.f;
  for (int ks = 0; ks < KS; ks++) s += bf2f(sl[((size_t)(ks * 72 + mt)) * 16384 + e]);
  float sc = g[o] * rsqrtf(vv[o] + 1e-5f);
  float valf = (s - mm[o]) * sc + bb[o];
  if (relu) valf = fmaxf(valf, 0.f);
  int b = mt / 36; int r = mt - b * 36;
  int h = (r / 6) * 16 + (m >> 4), w = (r % 6) * 16 + (m & 15);
  out[(((size_t)b * 96 + h) * 96 + w) * 64 + o] = f2bf(valf);
  if (do_proj){
    int px = tid >> 6;
    yl[px * 65 + o] = valf;
    __syncthreads();
    int m2 = ((blockIdx.x & 63) << 2) + px;
    int h2 = (r / 6) * 16 + (m2 >> 4), w2 = (r % 6) * 16 + (m2 & 15);
    size_t pix2 = ((size_t)b * 96 + h2) * 96 + w2;
    float va = 0.f;
    #pragma unroll 8
    for (int c = 0; c < 64; c++) va += wvL[o * 65 + c] * yl[px * 65 + c];
    v[pix2 * 64 + o] = f2bf(va);
    if (o < 16){
      const float* wsel = (o < 8) ? wqL : wkL;
      int d = o & 7;
      float qa = 0.f;
      #pragma unroll 8
      for (int c = 0; c < 64; c++) qa += wsel[d * 65 + c] * yl[px * 65 + c];
      if (o < 8) q[pix2 * 8 + d] = qa; else k[pix2 * 8 + d] = qa;
    }
  }
}

// ---------------- K-split reduce + BN + fused cls2 (1x1 64->19) -> t19 f32 ----------------
__global__ __launch_bounds__(256) void bn_reduce_cls_kernel(const unsigned short* __restrict__ sl,
    int KS, const float* __restrict__ g, const float* __restrict__ bb,
    const float* __restrict__ mm, const float* __restrict__ vv,
    const float* __restrict__ w2, float* __restrict__ t19){
  __shared__ float yl[4][64];
  __shared__ float w2L[19 * 64];
  int tid = threadIdx.x;
  for (int i = tid; i < 1216; i += 256) w2L[i] = w2[i];
  int idx = blockIdx.x * 256 + tid;
  int mt = idx >> 14, e = idx & 16383;
  int o = e & 63;
  float s = 0.f;
  for (int ks = 0; ks < KS; ks++) s += bf2f(sl[((size_t)(ks * 72 + mt)) * 16384 + e]);
  float sc = g[o] * rsqrtf(vv[o] + 1e-5f);
  float valf = (s - mm[o]) * sc + bb[o];
  yl[tid >> 6][o] = valf;
  __syncthreads();
  if (tid < 76){
    int mq = tid / 19, j = tid - mq * 19;
    float a = 0.f;
    #pragma unroll 8
    for (int c = 0; c < 64; c++) a += w2L[j * 64 + c] * yl[mq][c];
    int m = ((blockIdx.x & 63) << 2) + mq;
    int b = mt / 36; int r = mt - b * 36;
    int h = (r / 6) * 16 + (m >> 4), w = (r % 6) * 16 + (m & 15);
    t19[((size_t)(b * 19 + j)) * HW + h * 96 + w] = a;
  }
}

// ---------------- CCA: q,k,v projections (2 threads/pixel); v written bf16 ----------------
__global__ __launch_bounds__(256) void cca_proj_kernel(const unsigned short* __restrict__ xin,
    const float* __restrict__ wq, const float* __restrict__ wk, const float* __restrict__ wv,
    float* __restrict__ q, float* __restrict__ k, unsigned short* __restrict__ v){
  __shared__ float wqL[512], wkL[512], wvL[4096];
  int tid = threadIdx.x;
  for (int i = tid; i < 512; i += 256){ wqL[i] = wq[i]; wkL[i] = wk[i]; }
  for (int i = tid; i < 4096; i += 256) wvL[i] = wv[i];
  __syncthreads();
  int gid = blockIdx.x * 256 + tid;
  int gp = gid >> 1, half = gid & 1;
  unsigned short xv16[64];
  #pragma unroll
  for (int t = 0; t < 8; t++)
    *(s16x8*)(&xv16[t * 8]) = *(const s16x8*)(xin + (size_t)gp * 64 + t * 8);
  float qa[4], ka[4], va[32];
  #pragma unroll
  for (int d = 0; d < 4; d++){ qa[d] = 0.f; ka[d] = 0.f; }
  #pragma unroll
  for (int d = 0; d < 32; d++) va[d] = 0.f;
  int qo = half * 4, vo = half * 32;
  #pragma unroll 4
  for (int c = 0; c < 64; c++){
    float xv = bf2f(xv16[c]);
    #pragma unroll
    for (int d = 0; d < 4; d++){ qa[d] += wqL[(qo + d) * 64 + c] * xv; ka[d] += wkL[(qo + d) * 64 + c] * xv; }
    #pragma unroll
    for (int d = 0; d < 32; d++) va[d] += wvL[(vo + d) * 64 + c] * xv;
  }
  #pragma unroll
  for (int d = 0; d < 4; d++){ q[(size_t)gp * 8 + qo + d] = qa[d]; k[(size_t)gp * 8 + qo + d] = ka[d]; }
  #pragma unroll
  for (int t = 0; t < 4; t++){
    s16x8 pk;
    #pragma unroll
    for (int j = 0; j < 8; j++) pk[j] = (short)f2bf(va[t * 8 + j]);
    *(s16x8*)(v + (size_t)gp * 64 + vo + t * 8) = pk;
  }
}

// ---------------- CCA: row kernel — eH (inline) + eW + joint softmax + oW ----------------
__global__ __launch_bounds__(256, 2) void cca_rowSM_kernel(const float* __restrict__ qT,
    const float* __restrict__ kT, const unsigned short* __restrict__ vT,
    const unsigned short* __restrict__ xin, const float* __restrict__ gamma,
    float* __restrict__ ebuf, unsigned short* __restrict__ xout){
  int blk = blockIdx.x;                 // b*192 + h*2 + z
  int b = blk / 192; int r = blk - b * 192; int h = r >> 1, z = r & 1;
  __shared__ float qrL[48 * 12], krL[96 * 12];
  __shared__ float ewT[96 * 50];
  __shared__ float vLf[96 * 68];
  __shared__ float aWf[48 * 100];
  int tid = threadIdx.x;
  int lane = tid & 63, wvid = tid >> 6;
  size_t rowb = (size_t)(b * HW) + h * 96;
  const float* ebase = ebuf + rowb * 96;

  for (int i = tid; i < 384; i += 256){
    int wl = i >> 3, d = i & 7;
    qrL[wl * 12 + d] = qT[(rowb + z * 48 + wl) * 8 + d];
  }
  for (int i = tid; i < 768; i += 256){
    int wp = i >> 3, d = i & 7;
    krL[wp * 12 + d] = kT[(rowb + wp) * 8 + d];
  }
  for (int i = tid; i < 768; i += 256){
    int wp = i >> 3, oct = i & 7;
    s16x8 v8 = *(const s16x8*)(vT + (rowb + wp) * 64 + oct * 8);
    #pragma unroll
    for (int j = 0; j < 8; j++) vLf[wp * 68 + oct * 8 + j] = bf2f((unsigned short)v8[j]);
  }
  __syncthreads();
  {
    int wl0 = (tid & 15) * 3, kp0 = (tid >> 4) * 6;
    f32x4 q0[3], q1[3], k0[6], k1[6];
    #pragma unroll
    for (int i = 0; i < 3; i++){
      q0[i] = *(const f32x4*)&qrL[(wl0 + i) * 12];
      q1[i] = *(const f32x4*)&qrL[(wl0 + i) * 12 + 4];
    }
    #pragma unroll
    for (int j = 0; j < 6; j++){
      k0[j] = *(const f32x4*)&krL[(kp0 + j) * 12];
      k1[j] = *(const f32x4*)&krL[(kp0 + j) * 12 + 4];
    }
    #pragma unroll
    for (int j = 0; j < 6; j++)
      #pragma unroll
      for (int i = 0; i < 3; i++){
        float e = 0.f;
        #pragma unroll
        for (int d = 0; d < 4; d++) e += q0[i][d] * k0[j][d] + q1[i][d] * k1[j][d];
        ewT[(kp0 + j) * 50 + (wl0 + i)] = e;
      }
  }
  __syncthreads();
  #pragma unroll 2
  for (int t = 0; t < 12; t++){
    int wl = wvid + t * 4;
    int w = z * 48 + wl;
    f32x4 qa = *(const f32x4*)&qrL[wl * 12];
    f32x4 qb4 = *(const f32x4*)&qrL[wl * 12 + 4];
    const float* kc0 = kT + ((size_t)(b * HW) + (size_t)lane * 96 + w) * 8;
    f32x4 k0a = *(const f32x4*)kc0;
    f32x4 k0b = *(const f32x4*)(kc0 + 4);
    float x0 = 0.f;
    #pragma unroll
    for (int d = 0; d < 4; d++) x0 += qa[d] * k0a[d] + qb4[d] * k0b[d];
    if (lane == h) x0 = -1e30f;
    float x1;
    if (lane < 32){
      const float* kc1 = kT + ((size_t)(b * HW) + (size_t)(64 + lane) * 96 + w) * 8;
      f32x4 k1a = *(const f32x4*)kc1;
      f32x4 k1b = *(const f32x4*)(kc1 + 4);
      x1 = 0.f;
      #pragma unroll
      for (int d = 0; d < 4; d++) x1 += qa[d] * k1a[d] + qb4[d] * k1b[d];
      if (64 + lane == h) x1 = -1e30f;
    } else {
      x1 = ewT[(lane - 32) * 50 + wl];
    }
    float x2 = ewT[(lane + 32) * 50 + wl];
    float mx = fmaxf(x0, fmaxf(x1, x2));
    #pragma unroll
    for (int s = 32; s; s >>= 1) mx = fmaxf(mx, __shfl_xor(mx, s));
    float e0 = __expf(x0 - mx), e1 = __expf(x1 - mx), e2 = __expf(x2 - mx);
    float sm = e0 + e1 + e2;
    #pragma unroll
    for (int s = 32; s; s >>= 1) sm += __shfl_xor(sm, s);
    float inv = 1.f / sm;
    float* ebw = (float*)(ebase + (size_t)w * 96);
    ebw[lane] = e0 * inv;
    if (lane < 32) ebw[64 + lane] = e1 * inv;
    else           aWf[wl * 100 + (lane - 32)] = e1 * inv;
    aWf[wl * 100 + (lane + 32)] = e2 * inv;
  }
  __syncthreads();
  float gm = gamma[0];
  int d0 = (tid & 15) * 4, wl0 = (tid >> 4) * 3;
  f32x4 acc2[3];
  #pragma unroll
  for (int c = 0; c < 3; c++) acc2[c] = (f32x4)(0.f);
  for (int kp = 0; kp < 96; kp += 4){
    f32x4 a0 = *(const f32x4*)&aWf[(wl0 + 0) * 100 + kp];
    f32x4 a1 = *(const f32x4*)&aWf[(wl0 + 1) * 100 + kp];
    f32x4 a2 = *(const f32x4*)&aWf[(wl0 + 2) * 100 + kp];
    #pragma unroll
    for (int j = 0; j < 4; j++){
      f32x4 vv = *(const f32x4*)&vLf[(kp + j) * 68 + d0];
      acc2[0] += vv * a0[j];
      acc2[1] += vv * a1[j];
      acc2[2] += vv * a2[j];
    }
  }
  #pragma unroll
  for (int c = 0; c < 3; c++){
    size_t pix = rowb + z * 48 + wl0 + c;
    ushort4 xr = *(const ushort4*)&xin[pix * 64 + d0];
    ushort4 ov;
    ov.x = f2bf(bf2f(xr.x) + gm * acc2[c][0]);
    ov.y = f2bf(bf2f(xr.y) + gm * acc2[c][1]);
    ov.z = f2bf(bf2f(xr.z) + gm * acc2[c][2]);
    ov.w = f2bf(bf2f(xr.w) + gm * acc2[c][3]);
    *(ushort4*)&xout[pix * 64 + d0] = ov;
  }
}

// ---------------- CCA: column kernel — oH + final accumulate (h-half per block) ----------------
__global__ __launch_bounds__(256, 2) void cca_colO_kernel(const unsigned short* __restrict__ vT,
    const float* __restrict__ gamma, const float* __restrict__ ebuf,
    const unsigned short* __restrict__ xpart, unsigned short* __restrict__ xout){
  int blk = blockIdx.x;                 // b*192 + w*2 + z
  int b = blk / 192; int r = blk - b * 192; int w = r >> 1, z = r & 1;
  __shared__ float vLf[96 * 68];
  __shared__ float aTf[48 * 100];
  int tid = threadIdx.x;
  for (int i = tid; i < 768; i += 256){
    int kp = i >> 3, oct = i & 7;
    s16x8 v8 = *(const s16x8*)(vT + ((size_t)(b * HW) + kp * 96 + w) * 64 + oct * 8);
    #pragma unroll
    for (int j = 0; j < 8; j++) vLf[kp * 68 + oct * 8 + j] = bf2f((unsigned short)v8[j]);
  }
  for (int i = tid; i < 4608; i += 256){
    int hl = i / 96, kp = i - hl * 96;
    aTf[hl * 100 + kp] = ebuf[(((size_t)b * 96 + z * 48 + hl) * 96 + w) * 96 + kp];
  }
  __syncthreads();
  float gm = gamma[0];
  int d0 = (tid & 15) * 4, hl0 = (tid >> 4) * 3;
  f32x4 acc2[3];
  #pragma unroll
  for (int c = 0; c < 3; c++) acc2[c] = (f32x4)(0.f);
  for (int kp = 0; kp < 96; kp += 4){
    f32x4 a0 = *(const f32x4*)&aTf[(hl0 + 0) * 100 + kp];
    f32x4 a1 = *(const f32x4*)&aTf[(hl0 + 1) * 100 + kp];
    f32x4 a2 = *(const f32x4*)&aTf[(hl0 + 2) * 100 + kp];
    #pragma unroll
    for (int j = 0; j < 4; j++){
      f32x4 vv = *(const f32x4*)&vLf[(kp + j) * 68 + d0];
      acc2[0] += vv * a0[j];
      acc2[1] += vv * a1[j];
      acc2[2] += vv * a2[j];
    }
  }
  #pragma unroll
  for (int c = 0; c < 3; c++){
    size_t pix = (size_t)(b * HW) + (z * 48 + hl0 + c) * 96 + w;
    ushort4 xr = *(const ushort4*)&xpart[pix * 64 + d0];
    ushort4 ov;
    ov.x = f2bf(bf2f(xr.x) + gm * acc2[c][0]);
    ov.y = f2bf(bf2f(xr.y) + gm * acc2[c][1]);
    ov.z = f2bf(bf2f(xr.z) + gm * acc2[c][2]);
    ov.w = f2bf(bf2f(xr.w) + gm * acc2[c][3]);
    *(ushort4*)&xout[pix * 64 + d0] = ov;
  }
}

// ---------------- bilinear x8 upsample (align_corners) of 19ch ----------------
__global__ void upsample_kernel(const float* __restrict__ t19, float* __restrict__ out){
  int gid = blockIdx.x * 256 + threadIdx.x;
  int xq = gid % 192; int t = gid / 192;
  int yy = t % 768; t /= 768;
  int o = t % 19; int b = t / 19;
  const float R = 95.0f / 767.0f;
  float ry = yy * R;
  int iy = (int)ry;
  float fy = ry - (float)iy;
  int iy1 = min(iy + 1, 95);
  const float* base = t19 + ((size_t)b * 19 + o) * HW;
  float4 res;
  float* rp = (float*)&res;
  #pragma unroll
  for (int j = 0; j < 4; j++){
    int xx = xq * 4 + j;
    float rx = xx * R;
    int ix = (int)rx; float fx = rx - (float)ix; int ix1 = min(ix + 1, 95);
    float v00 = base[iy * 96 + ix],  v01 = base[iy * 96 + ix1];
    float v10 = base[iy1 * 96 + ix], v11 = base[iy1 * 96 + ix1];
    rp[j] = (1.f - fy) * ((1.f - fx) * v00 + fx * v01) + fy * ((1.f - fx) * v10 + fx * v11);
  }
  *(float4*)(out + (((size_t)b * 19 + o) * 768 + yy) * 768 + xq * 4) = res;
}

// ---------------- host-side orchestration ----------------
extern "C" void kernel_launch(void* const* d_in, const int* in_sizes, int n_in,
                              void* d_out, int out_size, void* d_ws, size_t ws_size,
                              hipStream_t stream){
  const float* x       = (const float*)d_in[0];
  const float* w_in    = (const float*)d_in[1];
  const float* bn_in_g = (const float*)d_in[2];
  const float* bn_in_b = (const float*)d_in[3];
  const float* bn_in_m = (const float*)d_in[4];
  const float* bn_in_v = (const float*)d_in[5];
  const float* wq      = (const float*)d_in[6];
  const float* wk      = (const float*)d_in[7];
  const float* wv      = (const float*)d_in[8];
  const float* gamma   = (const float*)d_in[9];
  const float* w_out   = (const float*)d_in[10];
  const float* bn_o_g  = (const float*)d_in[11];
  const float* bn_o_b  = (const float*)d_in[12];
  const float* bn_o_m  = (const float*)d_in[13];
  const float* bn_o_v  = (const float*)d_in[14];
  const float* w_cls1  = (const float*)d_in[15];
  const float* bn_c_g  = (const float*)d_in[16];
  const float* bn_c_b  = (const float*)d_in[17];
  const float* bn_c_m  = (const float*)d_in[18];
  const float* bn_c_v  = (const float*)d_in[19];
  const float* w_cls2  = (const float*)d_in[20];
  float* out = (float*)d_out;

  char* ws = (char*)d_ws;
  size_t off = 0;
  auto alloc = [&](size_t bytes) -> void* {
    void* p = ws + off; off += (bytes + 255) & ~(size_t)255; return p;
  };
  const int KS = 12;
  const size_t NHWCb = (size_t)2 * HW * 64 * 2;
  unsigned short* xT   = (unsigned short*)alloc((size_t)2 * HW * 2048 * 2);
  unsigned short* sl   = (unsigned short*)alloc((size_t)KS * 72 * 16384 * 2);
  float* ebuf = (float*)sl;                                     // CCA-phase reuse
  unsigned short* xattA = (unsigned short*)alloc(NHWCb);
  unsigned short* xattB = (unsigned short*)alloc(NHWCb);
  unsigned short* Ptmp  = (unsigned short*)alloc(NHWCb);
  unsigned short* attT  = (unsigned short*)alloc(NHWCb);
  unsigned short* midT  = (unsigned short*)alloc(NHWCb);
  float* qb    = (float*)alloc((size_t)2 * HW * 8 * 4);
  float* kb    = (float*)alloc((size_t)2 * HW * 8 * 4);
  unsigned short* vb = (unsigned short*)alloc(NHWCb);
  float* t19   = (float*)alloc((size_t)2 * 19 * HW * 4);
  unsigned short* WpIn  = (unsigned short*)alloc((size_t)64 * 2048 * 9 * 2);
  unsigned short* WpOut = (unsigned short*)alloc((size_t)64 * 64 * 9 * 2);
  unsigned short* WpCls = (unsigned short*)alloc((size_t)64 * 2112 * 9 * 2);
  unsigned short* zp    = (unsigned short*)alloc(256);
  (void)ws_size; (void)in_sizes; (void)n_in; (void)out_size;

  transp_pack_kernel<<<2304 + 512, 256, 0, stream>>>(x, xT, w_in, w_out, w_cls1,
      WpIn, WpOut, WpCls, zp);

  // conv_in (2048 -> 64) + BN + ReLU -> xattA ; fused proj #1 -> qb/kb/vb
  conv_nhwc_kernel<<<dim3(72, KS), 512, 0, stream>>>(xT, 2048, nullptr, 64, WpIn, sl, 64, zp);
  bn_reduce_kernel<<<4608, 256, 0, stream>>>(sl, KS, bn_in_g, bn_in_b, bn_in_m, bn_in_v, 1,
      xattA, 1, wq, wk, wv, qb, kb, vb);

  // CCA pass 1 (rowSM computes eH inline; colE eliminated)
  cca_rowSM_kernel<<<384, 256, 0, stream>>>(qb, kb, vb, xattA, gamma, ebuf, Ptmp);
  cca_colO_kernel<<<384, 256, 0, stream>>>(vb, gamma, ebuf, Ptmp, xattB);
  // CCA pass 2
  cca_proj_kernel<<<144, 256, 0, stream>>>(xattB, wq, wk, wv, qb, kb, vb);
  cca_rowSM_kernel<<<384, 256, 0, stream>>>(qb, kb, vb, xattB, gamma, ebuf, Ptmp);
  cca_colO_kernel<<<384, 256, 0, stream>>>(vb, gamma, ebuf, Ptmp, attT);

  // conv_out (64 -> 64) + fused BN + ReLU -> midT (single kernel, KS=1)
  conv_out_kernel<<<72, 256, 0, stream>>>(attT, WpOut, bn_o_g, bn_o_b, bn_o_m, bn_o_v, midT, zp);

  // cls1 conv on concat([x, mid]) (2112 -> 64) + BN + fused cls2 -> t19
  conv_nhwc_kernel<<<dim3(72, KS), 512, 0, stream>>>(xT, 2048, midT, 64, WpCls, sl, 66, zp);
  bn_reduce_cls_kernel<<<4608, 256, 0, stream>>>(sl, KS, bn_c_g, bn_c_b, bn_c_m, bn_c_v, w_cls2, t19);

  // bilinear x8 upsample of 19ch (commuted with 1x1 conv)
  upsample_kernel<<<21888, 256, 0, stream>>>(t19, out);
}

// Round 20
// 386.286 us; speedup vs baseline: 1.2884x; 1.2884x over previous
//
#include <hip/hip_runtime.h>
#include <stdint.h>

#define HW 9216   // 96*96

typedef float f32x4 __attribute__((ext_vector_type(4)));
typedef short s16x8 __attribute__((ext_vector_type(8)));

#define PIN() asm volatile("" ::: "memory")
#define WAITV12() asm volatile("s_waitcnt vmcnt(12)" ::: "memory")

__device__ __forceinline__ unsigned short f2bf(float f){
  union { float fv; uint32_t u; } x; x.fv = f;
  uint32_t u = x.u;
  u += 0x7fffu + ((u >> 16) & 1u);   // RNE
  return (unsigned short)(u >> 16);
}
__device__ __forceinline__ float bf2f(unsigned short s){
  union { uint32_t u; float fv; } x; x.u = ((uint32_t)s) << 16;
  return x.fv;
}

__device__ __forceinline__ void gload16(const void* g, void* l){
  __builtin_amdgcn_global_load_lds(
    (const __attribute__((address_space(1))) unsigned int*)g,
    (__attribute__((address_space(3))) unsigned int*)l, 16, 0, 0);
}

// ------- fused: NCHW->NHWC transpose (blocks 0..2303, pad 65 = 4-way reads) + packs + zp -------
__global__ __launch_bounds__(256) void transp_pack_kernel(const float* __restrict__ x,
    unsigned short* __restrict__ xT,
    const float* __restrict__ w_in, const float* __restrict__ w_out,
    const float* __restrict__ w_cls1, unsigned short* __restrict__ WpIn,
    unsigned short* __restrict__ WpOut, unsigned short* __restrict__ WpCls,
    unsigned short* __restrict__ zp){
  __shared__ unsigned short tl[256 * 65];
  int blk = blockIdx.x;
  int tid = threadIdx.x;
  if (blk < 2304){
    int b = blk / 1152; int r = blk - b * 1152;
    int cchunk = r / 144, pxt = r - cchunk * 144;
    int c0 = cchunk * 256, px0 = pxt * 64;
    for (int e = tid; e < 4096; e += 256){
      int cc = e >> 4, pq = e & 15;
      float4 v4 = *(const float4*)(x + ((size_t)(b * 2048 + c0 + cc)) * HW + px0 + pq * 4);
      const float* vp = (const float*)&v4;
      #pragma unroll
      for (int j = 0; j < 4; j++) tl[cc * 65 + pq * 4 + j] = f2bf(vp[j]);
    }
    __syncthreads();
    for (int j = tid; j < 2048; j += 256){
      int px = j >> 5, oct = j & 31;
      s16x8 pk;
      #pragma unroll
      for (int t = 0; t < 8; t++) pk[t] = (short)tl[(oct * 8 + t) * 65 + px];
      *(s16x8*)(xT + ((size_t)(b * 9216 + px0 + px)) * 2048 + c0 + oct * 8) = pk;
    }
  } else {
    if (blk == 2304 && tid < 64) ((unsigned int*)zp)[tid] = 0u;
    const int N0 = 64 * 2048 * 9, N1 = 64 * 64 * 9, N2 = 64 * 2112 * 9;
    int total = N0 + N1 + N2;
    int nblk = gridDim.x - 2304;
    for (int i = (blk - 2304) * 256 + tid; i < total; i += nblk * 256){
      const float* w; unsigned short* Wp; int Cin; int idx;
      if (i < N0){ w = w_in; Wp = WpIn; Cin = 2048; idx = i; }
      else if (i < N0 + N1){ w = w_out; Wp = WpOut; Cin = 64; idx = i - N0; }
      else { w = w_cls1; Wp = WpCls; Cin = 2112; idx = i - N0 - N1; }
      int c = idx & 31; int r = idx >> 5; int o = r & 63; int r2 = r >> 6;
      int tap = r2 % 9; int ck = r2 / 9;
      Wp[idx] = f2bf(w[((size_t)o * Cin + ck * 32 + c) * 9 + tap]);
    }
  }
}

// -------- per-tap body: NMF rows/wave, 4 ds_read + NMF*4 MFMA + rolling B prefetch --------
template<int T, int NMF>
__device__ __forceinline__ void tapbody(const char* hb, s16x8 (&bs)[4], f32x4 (&acc)[NMF][4],
    const unsigned short* wbase, int gmax, int g0, int rowbase, int ln, int kg){
  constexpr int dy = T / 3, dx = T - dy * 3;
  #pragma unroll
  for (int mf = 0; mf < NMF; mf++){
    int p = (rowbase + mf + dy) * 18 + (ln + dx);
    int aoff = p * 64 + ((kg ^ (p & 3)) << 4);
    s16x8 a = *(const s16x8*)(hb + aoff);
    #pragma unroll
    for (int nf = 0; nf < 4; nf++)
      acc[mf][nf] = __builtin_amdgcn_mfma_f32_16x16x32_bf16(a, bs[nf], acc[mf][nf], 0, 0, 0);
  }
  constexpr int dck = (T + 3) / 9, dt = (T + 3) % 9;
  if (g0 + T + 3 < gmax){
    const unsigned short* wb2 = wbase + dck * 18432 + dt * 2048;
    #pragma unroll
    for (int nf = 0; nf < 4; nf++) bs[nf] = *(const s16x8*)(wb2 + nf * 512);
  }
}

// ---------------- conv3x3 NHWC implicit GEMM (round-12 proven config, 256 thr) ----------------
__global__ __launch_bounds__(256, 2) void conv_nhwc_kernel(
    const unsigned short* __restrict__ A0, int c0stride,
    const unsigned short* __restrict__ A1, int nck0,
    const unsigned short* __restrict__ Wp,
    unsigned short* __restrict__ sl, int nchunks,
    const unsigned short* __restrict__ zp){
  int mt = blockIdx.x;
  int b = mt / 36; int r = mt - b * 36;
  int h0 = (r / 6) * 16, w0 = (r % 6) * 16;
  int KS = gridDim.y, ks = blockIdx.y;
  int c0 = (nchunks * ks) / KS, c1 = (nchunks * (ks + 1)) / KS;
  int tid = threadIdx.x, lane = tid & 63, wv = tid >> 6;
  int ln = lane & 15, kg = lane >> 4;
  __shared__ char halo[2][24576];

  int pixb0[6], pixb1[6]; bool val[6];
  #pragma unroll
  for (int rr = 0; rr < 6; rr++){
    int i = tid + rr * 256;
    int p = i >> 2, q_lds = i & 3;
    int logq = q_lds ^ (p & 3);
    int hh = p / 18, ww = p - hh * 18;
    int h = h0 - 1 + hh, w = w0 - 1 + ww;
    bool v = (i < 1296) && ((unsigned)h < 96u) && ((unsigned)w < 96u);
    val[rr] = v;
    int pix = (b * 96 + h) * 96 + w;
    pixb0[rr] = v ? (pix * c0stride * 2 + logq * 16) : 0;
    pixb1[rr] = v ? (pix * 128 + logq * 16) : 0;
  }
  const char* a0B = (const char*)A0;
  const char* a1B = (const char*)A1;
  const char* zpB = (const char*)zp;

  auto stage = [&](char* ldsB, int ck){
    bool inA0 = (ck < nck0);
    int chb0 = ck * 64, chb1 = (ck - nck0) * 64;
    #pragma unroll
    for (int rr = 0; rr < 6; rr++){
      const char* src = zpB;
      if (val[rr]) src = inA0 ? (a0B + pixb0[rr] + chb0) : (a1B + pixb1[rr] + chb1);
      gload16(src, ldsB + (tid + rr * 256) * 16);
    }
  };

  f32x4 acc[4][4];
  #pragma unroll
  for (int i = 0; i < 4; i++)
    #pragma unroll
    for (int j = 0; j < 4; j++) acc[i][j] = (f32x4)(0.f);

  s16x8 bs0[4], bs1[4], bs2[4];
  int gmax = (c1 - c0) * 9;
  int rowbase = wv * 4;

  stage(&halo[0][0], c0);
  PIN();
  {
    const unsigned short* w0b = Wp + (size_t)c0 * 18432 + ln * 32 + kg * 8;
    #pragma unroll
    for (int nf = 0; nf < 4; nf++){
      bs0[nf] = *(const s16x8*)(w0b + 0 * 2048 + nf * 512);
      bs1[nf] = *(const s16x8*)(w0b + 1 * 2048 + nf * 512);
      bs2[nf] = *(const s16x8*)(w0b + 2 * 2048 + nf * 512);
    }
  }
  WAITV12();
  __builtin_amdgcn_s_barrier();

  for (int ck = c0; ck < c1; ck++){
    int cur = (ck - c0) & 1;
    if (ck + 1 < c1){ stage(&halo[cur ^ 1][0], ck + 1); PIN(); }
    const unsigned short* wbase = Wp + (size_t)ck * 18432 + ln * 32 + kg * 8;
    const char* hb = &halo[cur][0];
    int g0 = (ck - c0) * 9;
    tapbody<0,4>(hb, bs0, acc, wbase, gmax, g0, rowbase, ln, kg);
    tapbody<1,4>(hb, bs1, acc, wbase, gmax, g0, rowbase, ln, kg);
    tapbody<2,4>(hb, bs2, acc, wbase, gmax, g0, rowbase, ln, kg);
    tapbody<3,4>(hb, bs0, acc, wbase, gmax, g0, rowbase, ln, kg);
    tapbody<4,4>(hb, bs1, acc, wbase, gmax, g0, rowbase, ln, kg);
    tapbody<5,4>(hb, bs2, acc, wbase, gmax, g0, rowbase, ln, kg);
    tapbody<6,4>(hb, bs0, acc, wbase, gmax, g0, rowbase, ln, kg);
    tapbody<7,4>(hb, bs1, acc, wbase, gmax, g0, rowbase, ln, kg);
    tapbody<8,4>(hb, bs2, acc, wbase, gmax, g0, rowbase, ln, kg);
    if (ck + 1 < c1){
      WAITV12();
      __builtin_amdgcn_s_barrier();
    }
  }

  unsigned short* base = sl + ((size_t)(ks * 72 + mt)) * 16384;
  #pragma unroll
  for (int mf = 0; mf < 4; mf++)
    #pragma unroll
    for (int nf = 0; nf < 4; nf++){
      int o = nf * 16 + ln;
      #pragma unroll
      for (int rr = 0; rr < 4; rr++){
        int m = (rowbase + mf) * 16 + kg * 4 + rr;
        base[m * 64 + o] = f2bf(acc[mf][nf][rr]);
      }
    }
}

// ---------------- conv_out (64->64, 2 chunks, KS=1, 256 thr) with fused BN+ReLU ----------------
__global__ __launch_bounds__(256, 2) void conv_out_kernel(
    const unsigned short* __restrict__ A0,
    const unsigned short* __restrict__ Wp,
    const float* __restrict__ g, const float* __restrict__ bb,
    const float* __restrict__ mm, const float* __restrict__ vv,
    unsigned short* __restrict__ outT,
    const unsigned short* __restrict__ zp){
  int mt = blockIdx.x;
  int b = mt / 36; int r = mt - b * 36;
  int h0 = (r / 6) * 16, w0 = (r % 6) * 16;
  int tid = threadIdx.x, lane = tid & 63, wv = tid >> 6;
  int ln = lane & 15, kg = lane >> 4;
  __shared__ char halo[2][24576];

  int pixb0[6]; bool val[6];
  #pragma unroll
  for (int rr = 0; rr < 6; rr++){
    int i = tid + rr * 256;
    int p = i >> 2, q_lds = i & 3;
    int logq = q_lds ^ (p & 3);
    int hh = p / 18, ww = p - hh * 18;
    int h = h0 - 1 + hh, w = w0 - 1 + ww;
    bool v = (i < 1296) && ((unsigned)h < 96u) && ((unsigned)w < 96u);
    val[rr] = v;
    int pix = (b * 96 + h) * 96 + w;
    pixb0[rr] = v ? (pix * 128 + logq * 16) : 0;
  }
  const char* a0B = (const char*)A0;
  const char* zpB = (const char*)zp;

  auto stage = [&](char* ldsB, int ck){
    int chb0 = ck * 64;
    #pragma unroll
    for (int rr = 0; rr < 6; rr++){
      const char* src = val[rr] ? (a0B + pixb0[rr] + chb0) : zpB;
      gload16(src, ldsB + (tid + rr * 256) * 16);
    }
  };

  f32x4 acc[4][4];
  #pragma unroll
  for (int i = 0; i < 4; i++)
    #pragma unroll
    for (int j = 0; j < 4; j++) acc[i][j] = (f32x4)(0.f);

  s16x8 bs0[4], bs1[4], bs2[4];
  int rowbase = wv * 4;

  stage(&halo[0][0], 0);
  PIN();
  {
    const unsigned short* w0b = Wp + ln * 32 + kg * 8;
    #pragma unroll
    for (int nf = 0; nf < 4; nf++){
      bs0[nf] = *(const s16x8*)(w0b + 0 * 2048 + nf * 512);
      bs1[nf] = *(const s16x8*)(w0b + 1 * 2048 + nf * 512);
      bs2[nf] = *(const s16x8*)(w0b + 2 * 2048 + nf * 512);
    }
  }
  WAITV12();
  __builtin_amdgcn_s_barrier();

  for (int ck = 0; ck < 2; ck++){
    int cur = ck & 1;
    if (ck == 0){ stage(&halo[1][0], 1); PIN(); }
    const unsigned short* wbase = Wp + (size_t)ck * 18432 + ln * 32 + kg * 8;
    const char* hb = &halo[cur][0];
    int g0 = ck * 9;
    tapbody<0,4>(hb, bs0, acc, wbase, 18, g0, rowbase, ln, kg);
    tapbody<1,4>(hb, bs1, acc, wbase, 18, g0, rowbase, ln, kg);
    tapbody<2,4>(hb, bs2, acc, wbase, 18, g0, rowbase, ln, kg);
    tapbody<3,4>(hb, bs0, acc, wbase, 18, g0, rowbase, ln, kg);
    tapbody<4,4>(hb, bs1, acc, wbase, 18, g0, rowbase, ln, kg);
    tapbody<5,4>(hb, bs2, acc, wbase, 18, g0, rowbase, ln, kg);
    tapbody<6,4>(hb, bs0, acc, wbase, 18, g0, rowbase, ln, kg);
    tapbody<7,4>(hb, bs1, acc, wbase, 18, g0, rowbase, ln, kg);
    tapbody<8,4>(hb, bs2, acc, wbase, 18, g0, rowbase, ln, kg);
    if (ck == 0){
      WAITV12();
      __builtin_amdgcn_s_barrier();
    }
  }

  #pragma unroll
  for (int nf = 0; nf < 4; nf++){
    int o = nf * 16 + ln;
    float sc = g[o] * rsqrtf(vv[o] + 1e-5f);
    float mo = mm[o], bo = bb[o];
    #pragma unroll
    for (int mf = 0; mf < 4; mf++)
      #pragma unroll
      for (int rr = 0; rr < 4; rr++){
        int m = (rowbase + mf) * 16 + kg * 4 + rr;
        int h = h0 + (m >> 4), w = w0 + (m & 15);
        float valf = (acc[mf][nf][rr] - mo) * sc + bo;
        valf = fmaxf(valf, 0.f);
        outT[(((size_t)b * 96 + h) * 96 + w) * 64 + o] = f2bf(valf);
      }
  }
}

// ---------------- K-split reduce + BN (+ReLU) -> NHWC bf16; optional fused q/k/v proj ----------------
__global__ __launch_bounds__(256) void bn_reduce_kernel(const unsigned short* __restrict__ sl,
    int KS, const float* __restrict__ g, const float* __restrict__ bb,
    const float* __restrict__ mm, const float* __restrict__ vv, int relu,
    unsigned short* __restrict__ out, int do_proj,
    const float* __restrict__ wq, const float* __restrict__ wk, const float* __restrict__ wv,
    float* __restrict__ q, float* __restrict__ k, unsigned short* __restrict__ v){
  __shared__ float yl[4 * 65];
  __shared__ float wqL[8 * 65], wkL[8 * 65], wvL[64 * 65];
  int tid = threadIdx.x;
  if (do_proj){
    for (int i = tid; i < 512; i += 256){
      int d = i >> 6, c = i & 63;
      wqL[d * 65 + c] = wq[i]; wkL[d * 65 + c] = wk[i];
    }
    for (int i = tid; i < 4096; i += 256){
      int o = i >> 6, c = i & 63;
      wvL[o * 65 + c] = wv[i];
    }
  }
  int idx = blockIdx.x * 256 + tid;
  int mt = idx >> 14, e = idx & 16383;
  int m = e >> 6, o = e & 63;
  float s = 0.f;
  for (int ks = 0; ks < KS; ks++) s += bf2f(sl[((size_t)(ks * 72 + mt)) * 16384 + e]);
  float sc = g[o] * rsqrtf(vv[o] + 1e-5f);
  float valf = (s - mm[o]) * sc + bb[o];
  if (relu) valf = fmaxf(valf, 0.f);
  int b = mt / 36; int r = mt - b * 36;
  int h = (r / 6) * 16 + (m >> 4), w = (r % 6) * 16 + (m & 15);
  out[(((size_t)b * 96 + h) * 96 + w) * 64 + o] = f2bf(valf);
  if (do_proj){
    int px = tid >> 6;
    yl[px * 65 + o] = valf;
    __syncthreads();
    int m2 = ((blockIdx.x & 63) << 2) + px;
    int h2 = (r / 6) * 16 + (m2 >> 4), w2 = (r % 6) * 16 + (m2 & 15);
    size_t pix2 = ((size_t)b * 96 + h2) * 96 + w2;
    float va = 0.f;
    #pragma unroll 8
    for (int c = 0; c < 64; c++) va += wvL[o * 65 + c] * yl[px * 65 + c];
    v[pix2 * 64 + o] = f2bf(va);
    if (o < 16){
      const float* wsel = (o < 8) ? wqL : wkL;
      int d = o & 7;
      float qa = 0.f;
      #pragma unroll 8
      for (int c = 0; c < 64; c++) qa += wsel[d * 65 + c] * yl[px * 65 + c];
      if (o < 8) q[pix2 * 8 + d] = qa; else k[pix2 * 8 + d] = qa;
    }
  }
}

// ---------------- K-split reduce + BN + fused cls2 (1x1 64->19) -> t19 f32 ----------------
__global__ __launch_bounds__(256) void bn_reduce_cls_kernel(const unsigned short* __restrict__ sl,
    int KS, const float* __restrict__ g, const float* __restrict__ bb,
    const float* __restrict__ mm, const float* __restrict__ vv,
    const float* __restrict__ w2, float* __restrict__ t19){
  __shared__ float yl[4][64];
  __shared__ float w2L[19 * 64];
  int tid = threadIdx.x;
  for (int i = tid; i < 1216; i += 256) w2L[i] = w2[i];
  int idx = blockIdx.x * 256 + tid;
  int mt = idx >> 14, e = idx & 16383;
  int o = e & 63;
  float s = 0.f;
  for (int ks = 0; ks < KS; ks++) s += bf2f(sl[((size_t)(ks * 72 + mt)) * 16384 + e]);
  float sc = g[o] * rsqrtf(vv[o] + 1e-5f);
  float valf = (s - mm[o]) * sc + bb[o];
  yl[tid >> 6][o] = valf;
  __syncthreads();
  if (tid < 76){
    int mq = tid / 19, j = tid - mq * 19;
    float a = 0.f;
    #pragma unroll 8
    for (int c = 0; c < 64; c++) a += w2L[j * 64 + c] * yl[mq][c];
    int m = ((blockIdx.x & 63) << 2) + mq;
    int b = mt / 36; int r = mt - b * 36;
    int h = (r / 6) * 16 + (m >> 4), w = (r % 6) * 16 + (m & 15);
    t19[((size_t)(b * 19 + j)) * HW + h * 96 + w] = a;
  }
}

// ---------------- CCA: q,k,v projections (2 threads/pixel); v written bf16 ----------------
__global__ __launch_bounds__(256) void cca_proj_kernel(const unsigned short* __restrict__ xin,
    const float* __restrict__ wq, const float* __restrict__ wk, const float* __restrict__ wv,
    float* __restrict__ q, float* __restrict__ k, unsigned short* __restrict__ v){
  __shared__ float wqL[512], wkL[512], wvL[4096];
  int tid = threadIdx.x;
  for (int i = tid; i < 512; i += 256){ wqL[i] = wq[i]; wkL[i] = wk[i]; }
  for (int i = tid; i < 4096; i += 256) wvL[i] = wv[i];
  __syncthreads();
  int gid = blockIdx.x * 256 + tid;
  int gp = gid >> 1, half = gid & 1;
  unsigned short xv16[64];
  #pragma unroll
  for (int t = 0; t < 8; t++)
    *(s16x8*)(&xv16[t * 8]) = *(const s16x8*)(xin + (size_t)gp * 64 + t * 8);
  float qa[4], ka[4], va[32];
  #pragma unroll
  for (int d = 0; d < 4; d++){ qa[d] = 0.f; ka[d] = 0.f; }
  #pragma unroll
  for (int d = 0; d < 32; d++) va[d] = 0.f;
  int qo = half * 4, vo = half * 32;
  #pragma unroll 4
  for (int c = 0; c < 64; c++){
    float xv = bf2f(xv16[c]);
    #pragma unroll
    for (int d = 0; d < 4; d++){ qa[d] += wqL[(qo + d) * 64 + c] * xv; ka[d] += wkL[(qo + d) * 64 + c] * xv; }
    #pragma unroll
    for (int d = 0; d < 32; d++) va[d] += wvL[(vo + d) * 64 + c] * xv;
  }
  #pragma unroll
  for (int d = 0; d < 4; d++){ q[(size_t)gp * 8 + qo + d] = qa[d]; k[(size_t)gp * 8 + qo + d] = ka[d]; }
  #pragma unroll
  for (int t = 0; t < 4; t++){
    s16x8 pk;
    #pragma unroll
    for (int j = 0; j < 8; j++) pk[j] = (short)f2bf(va[t * 8 + j]);
    *(s16x8*)(v + (size_t)gp * 64 + vo + t * 8) = pk;
  }
}

// ---------------- CCA: row kernel — eH (inline) + eW + joint softmax + oW ----------------
__global__ __launch_bounds__(256, 2) void cca_rowSM_kernel(const float* __restrict__ qT,
    const float* __restrict__ kT, const unsigned short* __restrict__ vT,
    const unsigned short* __restrict__ xin, const float* __restrict__ gamma,
    float* __restrict__ ebuf, unsigned short* __restrict__ xout){
  int blk = blockIdx.x;                 // b*192 + h*2 + z
  int b = blk / 192; int r = blk - b * 192; int h = r >> 1, z = r & 1;
  __shared__ float qrL[48 * 12], krL[96 * 12];
  __shared__ float ewT[96 * 50];
  __shared__ float vLf[96 * 68];
  __shared__ float aWf[48 * 100];
  int tid = threadIdx.x;
  int lane = tid & 63, wvid = tid >> 6;
  size_t rowb = (size_t)(b * HW) + h * 96;
  const float* ebase = ebuf + rowb * 96;

  for (int i = tid; i < 384; i += 256){
    int wl = i >> 3, d = i & 7;
    qrL[wl * 12 + d] = qT[(rowb + z * 48 + wl) * 8 + d];
  }
  for (int i = tid; i < 768; i += 256){
    int wp = i >> 3, d = i & 7;
    krL[wp * 12 + d] = kT[(rowb + wp) * 8 + d];
  }
  for (int i = tid; i < 768; i += 256){
    int wp = i >> 3, oct = i & 7;
    s16x8 v8 = *(const s16x8*)(vT + (rowb + wp) * 64 + oct * 8);
    #pragma unroll
    for (int j = 0; j < 8; j++) vLf[wp * 68 + oct * 8 + j] = bf2f((unsigned short)v8[j]);
  }
  __syncthreads();
  {
    int wl0 = (tid & 15) * 3, kp0 = (tid >> 4) * 6;
    f32x4 q0[3], q1[3], k0[6], k1[6];
    #pragma unroll
    for (int i = 0; i < 3; i++){
      q0[i] = *(const f32x4*)&qrL[(wl0 + i) * 12];
      q1[i] = *(const f32x4*)&qrL[(wl0 + i) * 12 + 4];
    }
    #pragma unroll
    for (int j = 0; j < 6; j++){
      k0[j] = *(const f32x4*)&krL[(kp0 + j) * 12];
      k1[j] = *(const f32x4*)&krL[(kp0 + j) * 12 + 4];
    }
    #pragma unroll
    for (int j = 0; j < 6; j++)
      #pragma unroll
      for (int i = 0; i < 3; i++){
        float e = 0.f;
        #pragma unroll
        for (int d = 0; d < 4; d++) e += q0[i][d] * k0[j][d] + q1[i][d] * k1[j][d];
        ewT[(kp0 + j) * 50 + (wl0 + i)] = e;
      }
  }
  __syncthreads();
  #pragma unroll 2
  for (int t = 0; t < 12; t++){
    int wl = wvid + t * 4;
    int w = z * 48 + wl;
    f32x4 qa = *(const f32x4*)&qrL[wl * 12];
    f32x4 qb4 = *(const f32x4*)&qrL[wl * 12 + 4];
    const float* kc0 = kT + ((size_t)(b * HW) + (size_t)lane * 96 + w) * 8;
    f32x4 k0a = *(const f32x4*)kc0;
    f32x4 k0b = *(const f32x4*)(kc0 + 4);
    float x0 = 0.f;
    #pragma unroll
    for (int d = 0; d < 4; d++) x0 += qa[d] * k0a[d] + qb4[d] * k0b[d];
    if (lane == h) x0 = -1e30f;
    float x1;
    if (lane < 32){
      const float* kc1 = kT + ((size_t)(b * HW) + (size_t)(64 + lane) * 96 + w) * 8;
      f32x4 k1a = *(const f32x4*)kc1;
      f32x4 k1b = *(const f32x4*)(kc1 + 4);
      x1 = 0.f;
      #pragma unroll
      for (int d = 0; d < 4; d++) x1 += qa[d] * k1a[d] + qb4[d] * k1b[d];
      if (64 + lane == h) x1 = -1e30f;
    } else {
      x1 = ewT[(lane - 32) * 50 + wl];
    }
    float x2 = ewT[(lane + 32) * 50 + wl];
    float mx = fmaxf(x0, fmaxf(x1, x2));
    #pragma unroll
    for (int s = 32; s; s >>= 1) mx = fmaxf(mx, __shfl_xor(mx, s));
    float e0 = __expf(x0 - mx), e1 = __expf(x1 - mx), e2 = __expf(x2 - mx);
    float sm = e0 + e1 + e2;
    #pragma unroll
    for (int s = 32; s; s >>= 1) sm += __shfl_xor(sm, s);
    float inv = 1.f / sm;
    float* ebw = (float*)(ebase + (size_t)w * 96);
    ebw[lane] = e0 * inv;
    if (lane < 32) ebw[64 + lane] = e1 * inv;
    else           aWf[wl * 100 + (lane - 32)] = e1 * inv;
    aWf[wl * 100 + (lane + 32)] = e2 * inv;
  }
  __syncthreads();
  float gm = gamma[0];
  int d0 = (tid & 15) * 4, wl0 = (tid >> 4) * 3;
  f32x4 acc2[3];
  #pragma unroll
  for (int c = 0; c < 3; c++) acc2[c] = (f32x4)(0.f);
  for (int kp = 0; kp < 96; kp += 4){
    f32x4 a0 = *(const f32x4*)&aWf[(wl0 + 0) * 100 + kp];
    f32x4 a1 = *(const f32x4*)&aWf[(wl0 + 1) * 100 + kp];
    f32x4 a2 = *(const f32x4*)&aWf[(wl0 + 2) * 100 + kp];
    #pragma unroll
    for (int j = 0; j < 4; j++){
      f32x4 vv = *(const f32x4*)&vLf[(kp + j) * 68 + d0];
      acc2[0] += vv * a0[j];
      acc2[1] += vv * a1[j];
      acc2[2] += vv * a2[j];
    }
  }
  #pragma unroll
  for (int c = 0; c < 3; c++){
    size_t pix = rowb + z * 48 + wl0 + c;
    ushort4 xr = *(const ushort4*)&xin[pix * 64 + d0];
    ushort4 ov;
    ov.x = f2bf(bf2f(xr.x) + gm * acc2[c][0]);
    ov.y = f2bf(bf2f(xr.y) + gm * acc2[c][1]);
    ov.z = f2bf(bf2f(xr.z) + gm * acc2[c][2]);
    ov.w = f2bf(bf2f(xr.w) + gm * acc2[c][3]);
    *(ushort4*)&xout[pix * 64 + d0] = ov;
  }
}

// ---------------- CCA: column kernel — oH + final accumulate (h-half per block) ----------------
__global__ __launch_bounds__(256, 2) void cca_colO_kernel(const unsigned short* __restrict__ vT,
    const float* __restrict__ gamma, const float* __restrict__ ebuf,
    const unsigned short* __restrict__ xpart, unsigned short* __restrict__ xout){
  int blk = blockIdx.x;                 // b*192 + w*2 + z
  int b = blk / 192; int r = blk - b * 192; int w = r >> 1, z = r & 1;
  __shared__ float vLf[96 * 68];
  __shared__ float aTf[48 * 100];
  int tid = threadIdx.x;
  for (int i = tid; i < 768; i += 256){
    int kp = i >> 3, oct = i & 7;
    s16x8 v8 = *(const s16x8*)(vT + ((size_t)(b * HW) + kp * 96 + w) * 64 + oct * 8);
    #pragma unroll
    for (int j = 0; j < 8; j++) vLf[kp * 68 + oct * 8 + j] = bf2f((unsigned short)v8[j]);
  }
  for (int i = tid; i < 4608; i += 256){
    int hl = i / 96, kp = i - hl * 96;
    aTf[hl * 100 + kp] = ebuf[(((size_t)b * 96 + z * 48 + hl) * 96 + w) * 96 + kp];
  }
  __syncthreads();
  float gm = gamma[0];
  int d0 = (tid & 15) * 4, hl0 = (tid >> 4) * 3;
  f32x4 acc2[3];
  #pragma unroll
  for (int c = 0; c < 3; c++) acc2[c] = (f32x4)(0.f);
  for (int kp = 0; kp < 96; kp += 4){
    f32x4 a0 = *(const f32x4*)&aTf[(hl0 + 0) * 100 + kp];
    f32x4 a1 = *(const f32x4*)&aTf[(hl0 + 1) * 100 + kp];
    f32x4 a2 = *(const f32x4*)&aTf[(hl0 + 2) * 100 + kp];
    #pragma unroll
    for (int j = 0; j < 4; j++){
      f32x4 vv = *(const f32x4*)&vLf[(kp + j) * 68 + d0];
      acc2[0] += vv * a0[j];
      acc2[1] += vv * a1[j];
      acc2[2] += vv * a2[j];
    }
  }
  #pragma unroll
  for (int c = 0; c < 3; c++){
    size_t pix = (size_t)(b * HW) + (z * 48 + hl0 + c) * 96 + w;
    ushort4 xr = *(const ushort4*)&xpart[pix * 64 + d0];
    ushort4 ov;
    ov.x = f2bf(bf2f(xr.x) + gm * acc2[c][0]);
    ov.y = f2bf(bf2f(xr.y) + gm * acc2[c][1]);
    ov.z = f2bf(bf2f(xr.z) + gm * acc2[c][2]);
    ov.w = f2bf(bf2f(xr.w) + gm * acc2[c][3]);
    *(ushort4*)&xout[pix * 64 + d0] = ov;
  }
}

// ---------------- bilinear x8 upsample (align_corners) of 19ch ----------------
__global__ void upsample_kernel(const float* __restrict__ t19, float* __restrict__ out){
  int gid = blockIdx.x * 256 + threadIdx.x;
  int xq = gid % 192; int t = gid / 192;
  int yy = t % 768; t /= 768;
  int o = t % 19; int b = t / 19;
  const float R = 95.0f / 767.0f;
  float ry = yy * R;
  int iy = (int)ry;
  float fy = ry - (float)iy;
  int iy1 = min(iy + 1, 95);
  const float* base = t19 + ((size_t)b * 19 + o) * HW;
  float4 res;
  float* rp = (float*)&res;
  #pragma unroll
  for (int j = 0; j < 4; j++){
    int xx = xq * 4 + j;
    float rx = xx * R;
    int ix = (int)rx; float fx = rx - (float)ix; int ix1 = min(ix + 1, 95);
    float v00 = base[iy * 96 + ix],  v01 = base[iy * 96 + ix1];
    float v10 = base[iy1 * 96 + ix], v11 = base[iy1 * 96 + ix1];
    rp[j] = (1.f - fy) * ((1.f - fx) * v00 + fx * v01) + fy * ((1.f - fx) * v10 + fx * v11);
  }
  *(float4*)(out + (((size_t)b * 19 + o) * 768 + yy) * 768 + xq * 4) = res;
}

// ---------------- host-side orchestration ----------------
extern "C" void kernel_launch(void* const* d_in, const int* in_sizes, int n_in,
                              void* d_out, int out_size, void* d_ws, size_t ws_size,
                              hipStream_t stream){
  const float* x       = (const float*)d_in[0];
  const float* w_in    = (const float*)d_in[1];
  const float* bn_in_g = (const float*)d_in[2];
  const float* bn_in_b = (const float*)d_in[3];
  const float* bn_in_m = (const float*)d_in[4];
  const float* bn_in_v = (const float*)d_in[5];
  const float* wq      = (const float*)d_in[6];
  const float* wk      = (const float*)d_in[7];
  const float* wv      = (const float*)d_in[8];
  const float* gamma   = (const float*)d_in[9];
  const float* w_out   = (const float*)d_in[10];
  const float* bn_o_g  = (const float*)d_in[11];
  const float* bn_o_b  = (const float*)d_in[12];
  const float* bn_o_m  = (const float*)d_in[13];
  const float* bn_o_v  = (const float*)d_in[14];
  const float* w_cls1  = (const float*)d_in[15];
  const float* bn_c_g  = (const float*)d_in[16];
  const float* bn_c_b  = (const float*)d_in[17];
  const float* bn_c_m  = (const float*)d_in[18];
  const float* bn_c_v  = (const float*)d_in[19];
  const float* w_cls2  = (const float*)d_in[20];
  float* out = (float*)d_out;

  char* ws = (char*)d_ws;
  size_t off = 0;
  auto alloc = [&](size_t bytes) -> void* {
    void* p = ws + off; off += (bytes + 255) & ~(size_t)255; return p;
  };
  const int KS = 12;
  const size_t NHWCb = (size_t)2 * HW * 64 * 2;
  unsigned short* xT   = (unsigned short*)alloc((size_t)2 * HW * 2048 * 2);
  unsigned short* sl   = (unsigned short*)alloc((size_t)KS * 72 * 16384 * 2);
  float* ebuf = (float*)sl;                                     // CCA-phase reuse
  unsigned short* xattA = (unsigned short*)alloc(NHWCb);
  unsigned short* xattB = (unsigned short*)alloc(NHWCb);
  unsigned short* Ptmp  = (unsigned short*)alloc(NHWCb);
  unsigned short* attT  = (unsigned short*)alloc(NHWCb);
  unsigned short* midT  = (unsigned short*)alloc(NHWCb);
  float* qb    = (float*)alloc((size_t)2 * HW * 8 * 4);
  float* kb    = (float*)alloc((size_t)2 * HW * 8 * 4);
  unsigned short* vb = (unsigned short*)alloc(NHWCb);
  float* t19   = (float*)alloc((size_t)2 * 19 * HW * 4);
  unsigned short* WpIn  = (unsigned short*)alloc((size_t)64 * 2048 * 9 * 2);
  unsigned short* WpOut = (unsigned short*)alloc((size_t)64 * 64 * 9 * 2);
  unsigned short* WpCls = (unsigned short*)alloc((size_t)64 * 2112 * 9 * 2);
  unsigned short* zp    = (unsigned short*)alloc(256);
  (void)ws_size; (void)in_sizes; (void)n_in; (void)out_size;

  transp_pack_kernel<<<2304 + 512, 256, 0, stream>>>(x, xT, w_in, w_out, w_cls1,
      WpIn, WpOut, WpCls, zp);

  // conv_in (2048 -> 64) + BN + ReLU -> xattA ; fused proj #1 -> qb/kb/vb
  conv_nhwc_kernel<<<dim3(72, KS), 256, 0, stream>>>(xT, 2048, nullptr, 64, WpIn, sl, 64, zp);
  bn_reduce_kernel<<<4608, 256, 0, stream>>>(sl, KS, bn_in_g, bn_in_b, bn_in_m, bn_in_v, 1,
      xattA, 1, wq, wk, wv, qb, kb, vb);

  // CCA pass 1 (rowSM computes eH inline; colE eliminated)
  cca_rowSM_kernel<<<384, 256, 0, stream>>>(qb, kb, vb, xattA, gamma, ebuf, Ptmp);
  cca_colO_kernel<<<384, 256, 0, stream>>>(vb, gamma, ebuf, Ptmp, xattB);
  // CCA pass 2
  cca_proj_kernel<<<144, 256, 0, stream>>>(xattB, wq, wk, wv, qb, kb, vb);
  cca_rowSM_kernel<<<384, 256, 0, stream>>>(qb, kb, vb, xattB, gamma, ebuf, Ptmp);
  cca_colO_kernel<<<384, 256, 0, stream>>>(vb, gamma, ebuf, Ptmp, attT);

  // conv_out (64 -> 64) + fused BN + ReLU -> midT (single kernel, KS=1)
  conv_out_kernel<<<72, 256, 0, stream>>>(attT, WpOut, bn_o_g, bn_o_b, bn_o_m, bn_o_v, midT, zp);

  // cls1 conv on concat([x, mid]) (2112 -> 64) + BN + fused cls2 -> t19
  conv_nhwc_kernel<<<dim3(72, KS), 256, 0, stream>>>(xT, 2048, midT, 64, WpCls, sl, 66, zp);
  bn_reduce_cls_kernel<<<4608, 256, 0, stream>>>(sl, KS, bn_c_g, bn_c_b, bn_c_m, bn_c_v, w_cls2, t19);

  // bilinear x8 upsample of 19ch (commuted with 1x1 conv)
  upsample_kernel<<<21888, 256, 0, stream>>>(t19, out);
}